// Round 1
// baseline (534.358 us; speedup 1.0000x reference)
//
#include <hip/hip_runtime.h>
#include <math.h>

#define NH 12
#define DH 64
#define SL 1024
#define NB 8
#define ED 768
#define NTAP 2047
#define NF 33
#define NSEQ 2048

__device__ __forceinline__ float2 cadd(float2 a, float2 b){ return make_float2(a.x+b.x, a.y+b.y); }
__device__ __forceinline__ float2 csub(float2 a, float2 b){ return make_float2(a.x-b.x, a.y-b.y); }
__device__ __forceinline__ float2 cmul(float2 a, float2 b){ return make_float2(a.x*b.x - a.y*b.y, a.x*b.y + a.y*b.x); }

// K1: softmax over taps (axis=1) per (h,e) column; write masked psfs to output 2.
__global__ void k1_softmax(const float* __restrict__ tp, float* __restrict__ psf_out) {
    __shared__ float col[NTAP];
    __shared__ float red[256];
    int c = blockIdx.x;            // 0..767
    int h = c >> 6, e = c & 63;
    const float* base = tp + (size_t)h * NTAP * 64 + e;
    float lmax = -1e30f;
    for (int s = threadIdx.x; s < NTAP; s += 256) {
        float v = base[(size_t)s * 64];
        col[s] = v;
        lmax = fmaxf(lmax, v);
    }
    red[threadIdx.x] = lmax;
    __syncthreads();
    for (int w = 128; w >= 1; w >>= 1) {
        if (threadIdx.x < w) red[threadIdx.x] = fmaxf(red[threadIdx.x], red[threadIdx.x + w]);
        __syncthreads();
    }
    float m = red[0];
    __syncthreads();
    float lsum = 0.f;
    for (int s = threadIdx.x; s < NTAP; s += 256) lsum += expf(col[s] - m);
    red[threadIdx.x] = lsum;
    __syncthreads();
    for (int w = 128; w >= 1; w >>= 1) {
        if (threadIdx.x < w) red[threadIdx.x] += red[threadIdx.x + w];
        __syncthreads();
    }
    float inv = 1.0f / red[0];
    float* ob = psf_out + (size_t)h * NTAP * 64 + e;
    for (int s = threadIdx.x; s < NTAP; s += 256) {
        float v = (s < SL) ? expf(col[s] - m) * inv : 0.0f;
        ob[(size_t)s * 64] = v;
    }
}

// K2: channel DFT-64 (forward, f=0..32) of masked psf; output Pc[h][f][s] (s<1024).
__global__ void k2_psf_cdft(const float* __restrict__ psf, float2* __restrict__ Pc) {
    __shared__ float p[64][65];
    __shared__ float2 tw[64];
    int s0 = blockIdx.x * 64;
    int h = blockIdx.y;
    for (int i = threadIdx.x; i < 64; i += 256) {
        float ang = 6.28318530717958647692f * (float)i / 64.0f;
        tw[i] = make_float2(cosf(ang), sinf(ang));
    }
    for (int i = threadIdx.x; i < 4096; i += 256) {
        int sl = i >> 6, e = i & 63;
        p[sl][e] = psf[((size_t)h * NTAP + (s0 + sl)) * 64 + e];
    }
    __syncthreads();
    for (int o = threadIdx.x; o < NF * 64; o += 256) {
        int f = o >> 6, sl = o & 63;
        float re = 0.f, im = 0.f;
        for (int e = 0; e < 64; ++e) {
            int m = (e * f) & 63;
            float v = p[sl][e];
            re += v * tw[m].x;
            im -= v * tw[m].y;
        }
        Pc[(size_t)(h * NF + f) * SL + (s0 + sl)] = make_float2(re, im);
    }
}

// K3: seq FFT-2048 (DIF, natural in -> bitrev out) of psf per (h,f); zero-padded.
__global__ void k3_psf_fft(const float2* __restrict__ Pc, float2* __restrict__ Pf) {
    __shared__ float2 buf[NSEQ];
    __shared__ float2 twd[1024];
    int h = blockIdx.x / NF, f = blockIdx.x % NF;
    for (int i = threadIdx.x; i < 1024; i += 256) {
        float ang = -6.28318530717958647692f * (float)i / 2048.0f;
        twd[i] = make_float2(cosf(ang), sinf(ang));
    }
    const float2* src = Pc + (size_t)(h * NF + f) * SL;
    for (int i = threadIdx.x; i < NSEQ; i += 256)
        buf[i] = (i < SL) ? src[i] : make_float2(0.f, 0.f);
    __syncthreads();
    for (int m = 1024; m >= 1; m >>= 1) {
        int stride = 1024 / m;
        for (int k = threadIdx.x; k < 1024; k += 256) {
            int j = k & (m - 1);
            int i0 = ((k - j) << 1) + j;
            int i1 = i0 + m;
            float2 a = buf[i0], b = buf[i1];
            float2 w = twd[j * stride];
            buf[i0] = cadd(a, b);
            buf[i1] = cmul(csub(a, b), w);
        }
        __syncthreads();
    }
    float2* dst = Pf + (size_t)(h * NF + f) * NSEQ;
    for (int i = threadIdx.x; i < NSEQ; i += 256) dst[i] = buf[i];
}

// K4: channel DFT-64 (forward, f=0..32) of emb; output Xc[(b*12+h)][f][t] (t<1024).
__global__ void k4_emb_cdft(const float* __restrict__ emb, float2* __restrict__ Xc) {
    __shared__ float x[64][65];
    __shared__ float2 tw[64];
    int t0 = blockIdx.x * 64;
    int bh = blockIdx.y;
    int b = bh / NH, h = bh % NH;
    for (int i = threadIdx.x; i < 64; i += 256) {
        float ang = 6.28318530717958647692f * (float)i / 64.0f;
        tw[i] = make_float2(cosf(ang), sinf(ang));
    }
    for (int i = threadIdx.x; i < 4096; i += 256) {
        int tl = i >> 6, e = i & 63;
        x[tl][e] = emb[((size_t)b * SL + (t0 + tl)) * ED + h * 64 + e];
    }
    __syncthreads();
    for (int o = threadIdx.x; o < NF * 64; o += 256) {
        int f = o >> 6, tl = o & 63;
        float re = 0.f, im = 0.f;
        for (int e = 0; e < 64; ++e) {
            int m = (e * f) & 63;
            float v = x[tl][e];
            re += v * tw[m].x;
            im -= v * tw[m].y;
        }
        Xc[(size_t)(bh * NF + f) * SL + (t0 + tl)] = make_float2(re, im);
    }
}

// K5: per (b,h,f): FFT-2048 (DIF) -> pointwise * Pf -> iFFT-2048 (DIT) -> write back t<1024 (in-place).
__global__ void k5_seq_conv(float2* __restrict__ Xc, const float2* __restrict__ Pf) {
    __shared__ float2 buf[NSEQ];
    __shared__ float2 twd[1024];
    int f = blockIdx.x % NF;
    int bh = blockIdx.x / NF;
    int h = bh % NH;
    for (int i = threadIdx.x; i < 1024; i += 256) {
        float ang = -6.28318530717958647692f * (float)i / 2048.0f;
        twd[i] = make_float2(cosf(ang), sinf(ang));
    }
    float2* xsl = Xc + (size_t)(bh * NF + f) * SL;
    for (int i = threadIdx.x; i < NSEQ; i += 256)
        buf[i] = (i < SL) ? xsl[i] : make_float2(0.f, 0.f);
    __syncthreads();
    // forward DIF
    for (int m = 1024; m >= 1; m >>= 1) {
        int stride = 1024 / m;
        for (int k = threadIdx.x; k < 1024; k += 256) {
            int j = k & (m - 1);
            int i0 = ((k - j) << 1) + j;
            int i1 = i0 + m;
            float2 a = buf[i0], b = buf[i1];
            float2 w = twd[j * stride];
            buf[i0] = cadd(a, b);
            buf[i1] = cmul(csub(a, b), w);
        }
        __syncthreads();
    }
    // pointwise multiply (both spectra in identical bit-reversed order)
    const float2* pf = Pf + (size_t)(h * NF + f) * NSEQ;
    for (int i = threadIdx.x; i < NSEQ; i += 256)
        buf[i] = cmul(buf[i], pf[i]);
    __syncthreads();
    // inverse DIT (bitrev in -> natural out), conj twiddles, 1/N at writeout
    for (int m = 1; m <= 1024; m <<= 1) {
        int stride = 1024 / m;
        for (int k = threadIdx.x; k < 1024; k += 256) {
            int j = k & (m - 1);
            int i0 = ((k - j) << 1) + j;
            int i1 = i0 + m;
            float2 w = twd[j * stride];
            w.y = -w.y;
            float2 a = buf[i0];
            float2 bm = cmul(buf[i1], w);
            buf[i0] = cadd(a, bm);
            buf[i1] = csub(a, bm);
        }
        __syncthreads();
    }
    const float scale = 1.0f / 2048.0f;
    for (int i = threadIdx.x; i < SL; i += 256) {
        float2 v = buf[i];
        xsl[i] = make_float2(v.x * scale, v.y * scale);
    }
}

// K6: inverse channel DFT-64 via Hermitian reconstruction (real part) + exact GELU -> G[8192][768].
__global__ void k6_icdft_gelu(const float2* __restrict__ Xc, float* __restrict__ G) {
    __shared__ float2 Y[NF][64];   // [f][t_local]
    __shared__ float2 tw[64];
    int t0 = blockIdx.x * 64;
    int bh = blockIdx.y;
    int b = bh / NH, h = bh % NH;
    for (int i = threadIdx.x; i < 64; i += 256) {
        float ang = 6.28318530717958647692f * (float)i / 64.0f;
        tw[i] = make_float2(cosf(ang), sinf(ang));
    }
    for (int i = threadIdx.x; i < NF * 64; i += 256) {
        int f = i >> 6, tl = i & 63;
        Y[f][tl] = Xc[(size_t)(bh * NF + f) * SL + t0 + tl];
    }
    __syncthreads();
    for (int o = threadIdx.x; o < 4096; o += 256) {
        int tl = o >> 6, e = o & 63;
        float acc = Y[0][tl].x + ((e & 1) ? -Y[32][tl].x : Y[32][tl].x);
        #pragma unroll 4
        for (int f = 1; f < 32; ++f) {
            float2 yf = Y[f][tl];
            int m = (e * f) & 63;
            acc += 2.0f * (yf.x * tw[m].x - yf.y * tw[m].y);
        }
        float v = acc * (1.0f / 64.0f);
        float g = 0.5f * v * (1.0f + erff(v * 0.70710678118654752440f));
        G[((size_t)b * SL + t0 + tl) * ED + h * 64 + e] = g;
    }
}

// K7: out[i][j] = sum_d G[i][d] * W[j][d] + bias[j]; fp32 tiled GEMM 64x64, 4x4/thread.
__global__ void k7_gemm(const float* __restrict__ Gm, const float* __restrict__ W,
                        const float* __restrict__ bias, float* __restrict__ out) {
    __shared__ float As[32][65];
    __shared__ float Bs[32][65];
    int i0 = blockIdx.y * 64;
    int j0 = blockIdx.x * 64;
    int ti = threadIdx.x >> 4, tj = threadIdx.x & 15;
    float acc[4][4] = {};
    for (int k0 = 0; k0 < ED; k0 += 32) {
        for (int idx = threadIdx.x; idx < 2048; idx += 256) {
            int r = idx >> 5, k = idx & 31;
            As[k][r] = Gm[(size_t)(i0 + r) * ED + k0 + k];
            Bs[k][r] = W[(size_t)(j0 + r) * ED + k0 + k];
        }
        __syncthreads();
        #pragma unroll
        for (int k = 0; k < 32; ++k) {
            float a[4], bb[4];
            #pragma unroll
            for (int m = 0; m < 4; ++m) a[m] = As[k][ti * 4 + m];
            #pragma unroll
            for (int n = 0; n < 4; ++n) bb[n] = Bs[k][tj * 4 + n];
            #pragma unroll
            for (int m = 0; m < 4; ++m)
                #pragma unroll
                for (int n = 0; n < 4; ++n)
                    acc[m][n] = fmaf(a[m], bb[n], acc[m][n]);
        }
        __syncthreads();
    }
    #pragma unroll
    for (int m = 0; m < 4; ++m)
        #pragma unroll
        for (int n = 0; n < 4; ++n)
            out[(size_t)(i0 + ti * 4 + m) * ED + j0 + tj * 4 + n] = acc[m][n] + bias[j0 + tj * 4 + n];
}

extern "C" void kernel_launch(void* const* d_in, const int* in_sizes, int n_in,
                              void* d_out, int out_size, void* d_ws, size_t ws_size,
                              hipStream_t stream) {
    (void)in_sizes; (void)n_in; (void)out_size; (void)ws_size;
    const float* emb  = (const float*)d_in[0];   // [8,1024,768]
    const float* tp   = (const float*)d_in[1];   // [12,2047,64]
    const float* W    = (const float*)d_in[2];   // [768,768]
    const float* bias = (const float*)d_in[3];   // [768]

    float* out_conv = (float*)d_out;                             // 8*1024*768
    float* out_psf  = out_conv + (size_t)NB * SL * ED;           // 12*2047*64

    // workspace layout (floats / float2):
    float2* Pc = (float2*)d_ws;                                  // 12*33*1024 complex
    float2* Pf = Pc + (size_t)NH * NF * SL;                      // 12*33*2048 complex
    float2* Xc = Pf + (size_t)NH * NF * NSEQ;                    // 96*33*1024 complex
    float*  G  = (float*)(Xc + (size_t)NB * NH * NF * SL);       // 8192*768 floats

    k1_softmax<<<dim3(NH * 64), dim3(256), 0, stream>>>(tp, out_psf);
    k2_psf_cdft<<<dim3(SL / 64, NH), dim3(256), 0, stream>>>(out_psf, Pc);
    k3_psf_fft<<<dim3(NH * NF), dim3(256), 0, stream>>>(Pc, Pf);
    k4_emb_cdft<<<dim3(SL / 64, NB * NH), dim3(256), 0, stream>>>(emb, Xc);
    k5_seq_conv<<<dim3(NB * NH * NF), dim3(256), 0, stream>>>(Xc, Pf);
    k6_icdft_gelu<<<dim3(SL / 64, NB * NH), dim3(256), 0, stream>>>(Xc, G);
    k7_gemm<<<dim3(ED / 64, (NB * SL) / 64), dim3(256), 0, stream>>>(G, W, bias, out_conv);
}

// Round 2
// 348.305 us; speedup vs baseline: 1.5342x; 1.5342x over previous
//
#include <hip/hip_runtime.h>
#include <hip/hip_bf16.h>
#include <math.h>

#define NH 12
#define DH 64
#define SL 1024
#define NB 8
#define ED 768
#define NTAP 2047
#define NF 33
#define NSEQ 2048

typedef __attribute__((ext_vector_type(8))) short bf16x8;
typedef __attribute__((ext_vector_type(4))) float f32x4;

#define GLB_U32(p) ((const __attribute__((address_space(1))) unsigned int*)(p))
#define LDS_U32(p) ((__attribute__((address_space(3))) unsigned int*)(p))

__device__ __forceinline__ float2 cadd(float2 a, float2 b){ return make_float2(a.x+b.x, a.y+b.y); }
__device__ __forceinline__ float2 csub(float2 a, float2 b){ return make_float2(a.x-b.x, a.y-b.y); }
__device__ __forceinline__ float2 cmul(float2 a, float2 b){ return make_float2(a.x*b.x - a.y*b.y, a.x*b.y + a.y*b.x); }

// K1: softmax over taps (axis=1) per (h,e) column; write masked psfs to output 2.
__global__ void k1_softmax(const float* __restrict__ tp, float* __restrict__ psf_out) {
    __shared__ float col[NTAP];
    __shared__ float red[256];
    int c = blockIdx.x;            // 0..767
    int h = c >> 6, e = c & 63;
    const float* base = tp + (size_t)h * NTAP * 64 + e;
    float lmax = -1e30f;
    for (int s = threadIdx.x; s < NTAP; s += 256) {
        float v = base[(size_t)s * 64];
        col[s] = v;
        lmax = fmaxf(lmax, v);
    }
    red[threadIdx.x] = lmax;
    __syncthreads();
    for (int w = 128; w >= 1; w >>= 1) {
        if (threadIdx.x < w) red[threadIdx.x] = fmaxf(red[threadIdx.x], red[threadIdx.x + w]);
        __syncthreads();
    }
    float m = red[0];
    __syncthreads();
    float lsum = 0.f;
    for (int s = threadIdx.x; s < NTAP; s += 256) lsum += expf(col[s] - m);
    red[threadIdx.x] = lsum;
    __syncthreads();
    for (int w = 128; w >= 1; w >>= 1) {
        if (threadIdx.x < w) red[threadIdx.x] += red[threadIdx.x + w];
        __syncthreads();
    }
    float inv = 1.0f / red[0];
    float* ob = psf_out + (size_t)h * NTAP * 64 + e;
    for (int s = threadIdx.x; s < NTAP; s += 256) {
        float v = (s < SL) ? expf(col[s] - m) * inv : 0.0f;
        ob[(size_t)s * 64] = v;
    }
}

// K2: channel DFT-64 (forward, f=0..32) of masked psf; output Pc[h][f][s] (s<1024).
__global__ void k2_psf_cdft(const float* __restrict__ psf, float2* __restrict__ Pc) {
    __shared__ float p[64][65];
    __shared__ float2 tw[64];
    int s0 = blockIdx.x * 64;
    int h = blockIdx.y;
    for (int i = threadIdx.x; i < 64; i += 256) {
        float ang = 6.28318530717958647692f * (float)i / 64.0f;
        tw[i] = make_float2(cosf(ang), sinf(ang));
    }
    for (int i = threadIdx.x; i < 4096; i += 256) {
        int sl = i >> 6, e = i & 63;
        p[sl][e] = psf[((size_t)h * NTAP + (s0 + sl)) * 64 + e];
    }
    __syncthreads();
    for (int o = threadIdx.x; o < NF * 64; o += 256) {
        int f = o >> 6, sl = o & 63;
        float re = 0.f, im = 0.f;
        for (int e = 0; e < 64; ++e) {
            int m = (e * f) & 63;
            float v = p[sl][e];
            re += v * tw[m].x;
            im -= v * tw[m].y;
        }
        Pc[(size_t)(h * NF + f) * SL + (s0 + sl)] = make_float2(re, im);
    }
}

// K3: seq FFT-2048 (DIF, natural in -> bitrev out) of psf per (h,f); zero-padded.
__global__ void k3_psf_fft(const float2* __restrict__ Pc, float2* __restrict__ Pf) {
    __shared__ float2 buf[NSEQ];
    __shared__ float2 twd[1024];
    int h = blockIdx.x / NF, f = blockIdx.x % NF;
    for (int i = threadIdx.x; i < 1024; i += 256) {
        float ang = -6.28318530717958647692f * (float)i / 2048.0f;
        twd[i] = make_float2(cosf(ang), sinf(ang));
    }
    const float2* src = Pc + (size_t)(h * NF + f) * SL;
    for (int i = threadIdx.x; i < NSEQ; i += 256)
        buf[i] = (i < SL) ? src[i] : make_float2(0.f, 0.f);
    __syncthreads();
    for (int m = 1024; m >= 1; m >>= 1) {
        int stride = 1024 / m;
        for (int k = threadIdx.x; k < 1024; k += 256) {
            int j = k & (m - 1);
            int i0 = ((k - j) << 1) + j;
            int i1 = i0 + m;
            float2 a = buf[i0], b = buf[i1];
            float2 w = twd[j * stride];
            buf[i0] = cadd(a, b);
            buf[i1] = cmul(csub(a, b), w);
        }
        __syncthreads();
    }
    float2* dst = Pf + (size_t)(h * NF + f) * NSEQ;
    for (int i = threadIdx.x; i < NSEQ; i += 256) dst[i] = buf[i];
}

// K4: channel DFT-64 (forward, f=0..32) of emb; output Xc[(b*12+h)][f][t] (t<1024).
__global__ void k4_emb_cdft(const float* __restrict__ emb, float2* __restrict__ Xc) {
    __shared__ float x[64][65];
    __shared__ float2 tw[64];
    int t0 = blockIdx.x * 64;
    int bh = blockIdx.y;
    int b = bh / NH, h = bh % NH;
    for (int i = threadIdx.x; i < 64; i += 256) {
        float ang = 6.28318530717958647692f * (float)i / 64.0f;
        tw[i] = make_float2(cosf(ang), sinf(ang));
    }
    for (int i = threadIdx.x; i < 4096; i += 256) {
        int tl = i >> 6, e = i & 63;
        x[tl][e] = emb[((size_t)b * SL + (t0 + tl)) * ED + h * 64 + e];
    }
    __syncthreads();
    for (int o = threadIdx.x; o < NF * 64; o += 256) {
        int f = o >> 6, tl = o & 63;
        float re = 0.f, im = 0.f;
        for (int e = 0; e < 64; ++e) {
            int m = (e * f) & 63;
            float v = x[tl][e];
            re += v * tw[m].x;
            im -= v * tw[m].y;
        }
        Xc[(size_t)(bh * NF + f) * SL + (t0 + tl)] = make_float2(re, im);
    }
}

// K5: per (b,h,f): FFT-2048 (DIF) -> pointwise * Pf -> iFFT-2048 (DIT) -> write back t<1024 (in-place).
__global__ void k5_seq_conv(float2* __restrict__ Xc, const float2* __restrict__ Pf) {
    __shared__ float2 buf[NSEQ];
    __shared__ float2 twd[1024];
    int f = blockIdx.x % NF;
    int bh = blockIdx.x / NF;
    int h = bh % NH;
    for (int i = threadIdx.x; i < 1024; i += 256) {
        float ang = -6.28318530717958647692f * (float)i / 2048.0f;
        twd[i] = make_float2(cosf(ang), sinf(ang));
    }
    float2* xsl = Xc + (size_t)(bh * NF + f) * SL;
    for (int i = threadIdx.x; i < NSEQ; i += 256)
        buf[i] = (i < SL) ? xsl[i] : make_float2(0.f, 0.f);
    __syncthreads();
    // forward DIF
    for (int m = 1024; m >= 1; m >>= 1) {
        int stride = 1024 / m;
        for (int k = threadIdx.x; k < 1024; k += 256) {
            int j = k & (m - 1);
            int i0 = ((k - j) << 1) + j;
            int i1 = i0 + m;
            float2 a = buf[i0], b = buf[i1];
            float2 w = twd[j * stride];
            buf[i0] = cadd(a, b);
            buf[i1] = cmul(csub(a, b), w);
        }
        __syncthreads();
    }
    // pointwise multiply (both spectra in identical bit-reversed order)
    const float2* pf = Pf + (size_t)(h * NF + f) * NSEQ;
    for (int i = threadIdx.x; i < NSEQ; i += 256)
        buf[i] = cmul(buf[i], pf[i]);
    __syncthreads();
    // inverse DIT (bitrev in -> natural out), conj twiddles, 1/N at writeout
    for (int m = 1; m <= 1024; m <<= 1) {
        int stride = 1024 / m;
        for (int k = threadIdx.x; k < 1024; k += 256) {
            int j = k & (m - 1);
            int i0 = ((k - j) << 1) + j;
            int i1 = i0 + m;
            float2 w = twd[j * stride];
            w.y = -w.y;
            float2 a = buf[i0];
            float2 bm = cmul(buf[i1], w);
            buf[i0] = cadd(a, bm);
            buf[i1] = csub(a, bm);
        }
        __syncthreads();
    }
    const float scale = 1.0f / 2048.0f;
    for (int i = threadIdx.x; i < SL; i += 256) {
        float2 v = buf[i];
        xsl[i] = make_float2(v.x * scale, v.y * scale);
    }
}

// K6: inverse channel DFT-64 (real part) + exact GELU -> G as bf16 hi/lo pair [8192][768].
__global__ void k6_icdft_gelu(const float2* __restrict__ Xc,
                              __hip_bfloat16* __restrict__ Gh, __hip_bfloat16* __restrict__ Gl) {
    __shared__ float2 Y[NF][64];   // [f][t_local]
    __shared__ float2 tw[64];
    int t0 = blockIdx.x * 64;
    int bh = blockIdx.y;
    int b = bh / NH, h = bh % NH;
    for (int i = threadIdx.x; i < 64; i += 256) {
        float ang = 6.28318530717958647692f * (float)i / 64.0f;
        tw[i] = make_float2(cosf(ang), sinf(ang));
    }
    for (int i = threadIdx.x; i < NF * 64; i += 256) {
        int f = i >> 6, tl = i & 63;
        Y[f][tl] = Xc[(size_t)(bh * NF + f) * SL + t0 + tl];
    }
    __syncthreads();
    for (int o = threadIdx.x; o < 4096; o += 256) {
        int tl = o >> 6, e = o & 63;
        float acc = Y[0][tl].x + ((e & 1) ? -Y[32][tl].x : Y[32][tl].x);
        #pragma unroll 4
        for (int f = 1; f < 32; ++f) {
            float2 yf = Y[f][tl];
            int m = (e * f) & 63;
            acc += 2.0f * (yf.x * tw[m].x - yf.y * tw[m].y);
        }
        float v = acc * (1.0f / 64.0f);
        float g = 0.5f * v * (1.0f + erff(v * 0.70710678118654752440f));
        size_t idx = ((size_t)b * SL + t0 + tl) * ED + h * 64 + e;
        __hip_bfloat16 hb = __float2bfloat16(g);
        Gh[idx] = hb;
        Gl[idx] = __float2bfloat16(g - __bfloat162float(hb));
    }
}

// K0b: cast W (fp32 [768][768]) to bf16 hi/lo pair.
__global__ void k0_castW(const float* __restrict__ W,
                         __hip_bfloat16* __restrict__ Wh, __hip_bfloat16* __restrict__ Wl) {
    int i = blockIdx.x * 256 + threadIdx.x;
    if (i < ED * ED) {
        float w = W[i];
        __hip_bfloat16 hb = __float2bfloat16(w);
        Wh[i] = hb;
        Wl[i] = __float2bfloat16(w - __bfloat162float(hb));
    }
}

// K7: out[i][j] = sum_d G[i][d]*W[j][d] + bias[j] via bf16 split-precision MFMA.
// 128x128 tile, 4 waves (2x2 of 64x64), BK=32, mfma_f32_16x16x32_bf16.
// acc += a_hi*b_hi + a_hi*b_lo + a_lo*b_hi  (a_lo*b_lo ~ 2^-18 rel, negligible)
__global__ __launch_bounds__(256) void k7_mfma(
        const ushort* __restrict__ Gh, const ushort* __restrict__ Gl,
        const ushort* __restrict__ Wh, const ushort* __restrict__ Wl,
        const float* __restrict__ bias, float* __restrict__ out) {
    __shared__ ushort Ah[128 * 32], Al[128 * 32], Bh[128 * 32], Bl[128 * 32];
    const int j0 = blockIdx.x * 128;
    const int i0 = blockIdx.y * 128;
    const int tid = threadIdx.x;
    const int lane = tid & 63, wid = tid >> 6;
    const int wm = wid >> 1, wn = wid & 1;          // 2x2 wave grid, each 64x64

    // staging geometry: each wave stages rows [wid*32, wid*32+32) of each 128x32 tile,
    // two global_load_lds rounds of 16 rows; lane l -> row += l>>2, kcol = (l&3)*8 elems.
    const int stRow = wid * 32 + (lane >> 2);
    const int stCol = (lane & 3) * 8;
    const int ldsBase0 = wid * 1024;                // ushort offset of round-0 dest
    const int ldsBase1 = wid * 1024 + 512;

    f32x4 acc[4][4] = {};

    const int arow = wm * 64 + (lane & 15);         // A fragment row within 128-tile
    const int brow = wn * 64 + (lane & 15);         // B fragment row within 128-tile
    const int kb8  = (lane >> 4) * 8;               // k offset (elements) within BK=32

    for (int k0 = 0; k0 < ED; k0 += 32) {
        const ushort* gA = Gh + (size_t)(i0 + stRow) * ED + k0 + stCol;
        const ushort* gAl = Gl + (size_t)(i0 + stRow) * ED + k0 + stCol;
        const ushort* gB = Wh + (size_t)(j0 + stRow) * ED + k0 + stCol;
        const ushort* gBl = Wl + (size_t)(j0 + stRow) * ED + k0 + stCol;
        __builtin_amdgcn_global_load_lds(GLB_U32(gA), LDS_U32(&Ah[ldsBase0]), 16, 0, 0);
        __builtin_amdgcn_global_load_lds(GLB_U32(gA + 16 * ED), LDS_U32(&Ah[ldsBase1]), 16, 0, 0);
        __builtin_amdgcn_global_load_lds(GLB_U32(gAl), LDS_U32(&Al[ldsBase0]), 16, 0, 0);
        __builtin_amdgcn_global_load_lds(GLB_U32(gAl + 16 * ED), LDS_U32(&Al[ldsBase1]), 16, 0, 0);
        __builtin_amdgcn_global_load_lds(GLB_U32(gB), LDS_U32(&Bh[ldsBase0]), 16, 0, 0);
        __builtin_amdgcn_global_load_lds(GLB_U32(gB + 16 * ED), LDS_U32(&Bh[ldsBase1]), 16, 0, 0);
        __builtin_amdgcn_global_load_lds(GLB_U32(gBl), LDS_U32(&Bl[ldsBase0]), 16, 0, 0);
        __builtin_amdgcn_global_load_lds(GLB_U32(gBl + 16 * ED), LDS_U32(&Bl[ldsBase1]), 16, 0, 0);
        __syncthreads();   // compiler drains vmcnt(0) before barrier

        bf16x8 ah[4], al[4], bh[4], bl[4];
        #pragma unroll
        for (int m = 0; m < 4; ++m) {
            ah[m] = *(const bf16x8*)&Ah[(arow + m * 16) * 32 + kb8];
            al[m] = *(const bf16x8*)&Al[(arow + m * 16) * 32 + kb8];
        }
        #pragma unroll
        for (int n = 0; n < 4; ++n) {
            bh[n] = *(const bf16x8*)&Bh[(brow + n * 16) * 32 + kb8];
            bl[n] = *(const bf16x8*)&Bl[(brow + n * 16) * 32 + kb8];
        }
        #pragma unroll
        for (int m = 0; m < 4; ++m)
            #pragma unroll
            for (int n = 0; n < 4; ++n) {
                acc[m][n] = __builtin_amdgcn_mfma_f32_16x16x32_bf16(ah[m], bh[n], acc[m][n], 0, 0, 0);
                acc[m][n] = __builtin_amdgcn_mfma_f32_16x16x32_bf16(ah[m], bl[n], acc[m][n], 0, 0, 0);
                acc[m][n] = __builtin_amdgcn_mfma_f32_16x16x32_bf16(al[m], bh[n], acc[m][n], 0, 0, 0);
            }
        __syncthreads();   // all reads done before next stage overwrites
    }

    // epilogue: D layout col = lane&15, row = (lane>>4)*4 + reg
    const int ocol0 = j0 + wn * 64 + (lane & 15);
    const int orow0 = i0 + wm * 64 + (lane >> 4) * 4;
    #pragma unroll
    for (int n = 0; n < 4; ++n) {
        const float bv = bias[ocol0 + n * 16];
        #pragma unroll
        for (int m = 0; m < 4; ++m) {
            #pragma unroll
            for (int j = 0; j < 4; ++j) {
                out[(size_t)(orow0 + m * 16 + j) * ED + ocol0 + n * 16] = acc[m][n][j] + bv;
            }
        }
    }
}

extern "C" void kernel_launch(void* const* d_in, const int* in_sizes, int n_in,
                              void* d_out, int out_size, void* d_ws, size_t ws_size,
                              hipStream_t stream) {
    (void)in_sizes; (void)n_in; (void)out_size; (void)ws_size;
    const float* emb  = (const float*)d_in[0];   // [8,1024,768]
    const float* tp   = (const float*)d_in[1];   // [12,2047,64]
    const float* W    = (const float*)d_in[2];   // [768,768]
    const float* bias = (const float*)d_in[3];   // [768]

    float* out_conv = (float*)d_out;                             // 8*1024*768
    float* out_psf  = out_conv + (size_t)NB * SL * ED;           // 12*2047*64

    // workspace layout:
    float2* Pc = (float2*)d_ws;                                  // 12*33*1024 complex (dead after k3)
    float2* Pf = Pc + (size_t)NH * NF * SL;                      // 12*33*2048 complex
    float2* Xc = Pf + (size_t)NH * NF * NSEQ;                    // 96*33*1024 complex
    __hip_bfloat16* Gh = (__hip_bfloat16*)(Xc + (size_t)NB * NH * NF * SL);  // 8192*768
    __hip_bfloat16* Gl = Gh + (size_t)NB * SL * ED;                          // 8192*768
    // W hi/lo overlaid on Pc (2.36 MB <= 3.24 MB), launched after k3 consumes Pc
    __hip_bfloat16* Whh = (__hip_bfloat16*)Pc;
    __hip_bfloat16* Wll = Whh + (size_t)ED * ED;

    k1_softmax<<<dim3(NH * 64), dim3(256), 0, stream>>>(tp, out_psf);
    k2_psf_cdft<<<dim3(SL / 64, NH), dim3(256), 0, stream>>>(out_psf, Pc);
    k3_psf_fft<<<dim3(NH * NF), dim3(256), 0, stream>>>(Pc, Pf);
    k0_castW<<<dim3((ED * ED + 255) / 256), dim3(256), 0, stream>>>(W, Whh, Wll);
    k4_emb_cdft<<<dim3(SL / 64, NB * NH), dim3(256), 0, stream>>>(emb, Xc);
    k5_seq_conv<<<dim3(NB * NH * NF), dim3(256), 0, stream>>>(Xc, Pf);
    k6_icdft_gelu<<<dim3(SL / 64, NB * NH), dim3(256), 0, stream>>>(Xc, Gh, Gl);
    k7_mfma<<<dim3(ED / 128, (NB * SL) / 128), dim3(256), 0, stream>>>(
        (const ushort*)Gh, (const ushort*)Gl, (const ushort*)Whh, (const ushort*)Wll,
        bias, out_conv);
}

// Round 3
// 224.424 us; speedup vs baseline: 2.3810x; 1.5520x over previous
//
#include <hip/hip_runtime.h>
#include <hip/hip_bf16.h>
#include <math.h>

#define NH 12
#define DH 64
#define SL 1024
#define NB 8
#define ED 768
#define NTAP 2047
#define NF 33
#define NSEQ 2048

typedef __attribute__((ext_vector_type(8))) short bf16x8;
typedef __attribute__((ext_vector_type(4))) float f32x4;

#define GLB_U32(p) ((const __attribute__((address_space(1))) unsigned int*)(p))
#define LDS_U32(p) ((__attribute__((address_space(3))) unsigned int*)(p))

__device__ __forceinline__ float2 cadd(float2 a, float2 b){ return make_float2(a.x+b.x, a.y+b.y); }
__device__ __forceinline__ float2 csub(float2 a, float2 b){ return make_float2(a.x-b.x, a.y-b.y); }
__device__ __forceinline__ float2 cmul(float2 a, float2 b){ return make_float2(a.x*b.x - a.y*b.y, a.x*b.y + a.y*b.x); }

__device__ __forceinline__ unsigned short bf16bits(float f) {
    __hip_bfloat16 hb = __float2bfloat16(f);
    return *reinterpret_cast<unsigned short*>(&hb);
}
__device__ __forceinline__ float bf16val(unsigned short u) {
    __hip_bfloat16 hb = *reinterpret_cast<__hip_bfloat16*>(&u);
    return __bfloat162float(hb);
}
// convert 8 fp32 -> bf16 hi + lo fragments
__device__ __forceinline__ void cvt8(const float* v, bf16x8& h8, bf16x8& l8) {
    #pragma unroll
    for (int j = 0; j < 8; ++j) {
        unsigned short hb = bf16bits(v[j]);
        h8[j] = (short)hb;
        l8[j] = (short)bf16bits(v[j] - bf16val(hb));
    }
}

// K1: softmax over taps (axis=1) per (h,e) column; write masked psfs to output 2.
__global__ void k1_softmax(const float* __restrict__ tp, float* __restrict__ psf_out) {
    __shared__ float col[NTAP];
    __shared__ float red[256];
    int c = blockIdx.x;            // 0..767
    int h = c >> 6, e = c & 63;
    const float* base = tp + (size_t)h * NTAP * 64 + e;
    float lmax = -1e30f;
    for (int s = threadIdx.x; s < NTAP; s += 256) {
        float v = base[(size_t)s * 64];
        col[s] = v;
        lmax = fmaxf(lmax, v);
    }
    red[threadIdx.x] = lmax;
    __syncthreads();
    for (int w = 128; w >= 1; w >>= 1) {
        if (threadIdx.x < w) red[threadIdx.x] = fmaxf(red[threadIdx.x], red[threadIdx.x + w]);
        __syncthreads();
    }
    float m = red[0];
    __syncthreads();
    float lsum = 0.f;
    for (int s = threadIdx.x; s < NTAP; s += 256) lsum += expf(col[s] - m);
    red[threadIdx.x] = lsum;
    __syncthreads();
    for (int w = 128; w >= 1; w >>= 1) {
        if (threadIdx.x < w) red[threadIdx.x] += red[threadIdx.x + w];
        __syncthreads();
    }
    float inv = 1.0f / red[0];
    float* ob = psf_out + (size_t)h * NTAP * 64 + e;
    for (int s = threadIdx.x; s < NTAP; s += 256) {
        float v = (s < SL) ? expf(col[s] - m) * inv : 0.0f;
        ob[(size_t)s * 64] = v;
    }
}

// K2: channel DFT-64 (forward, f=0..32) of masked psf; output Pc[h][f][s] (s<1024).
__global__ void k2_psf_cdft(const float* __restrict__ psf, float2* __restrict__ Pc) {
    __shared__ float p[64][65];
    __shared__ float2 tw[64];
    int s0 = blockIdx.x * 64;
    int h = blockIdx.y;
    for (int i = threadIdx.x; i < 64; i += 256) {
        float ang = 6.28318530717958647692f * (float)i / 64.0f;
        tw[i] = make_float2(cosf(ang), sinf(ang));
    }
    for (int i = threadIdx.x; i < 4096; i += 256) {
        int sl = i >> 6, e = i & 63;
        p[sl][e] = psf[((size_t)h * NTAP + (s0 + sl)) * 64 + e];
    }
    __syncthreads();
    for (int o = threadIdx.x; o < NF * 64; o += 256) {
        int f = o >> 6, sl = o & 63;
        float re = 0.f, im = 0.f;
        for (int e = 0; e < 64; ++e) {
            int m = (e * f) & 63;
            float v = p[sl][e];
            re += v * tw[m].x;
            im -= v * tw[m].y;
        }
        Pc[(size_t)(h * NF + f) * SL + (s0 + sl)] = make_float2(re, im);
    }
}

// K3: seq FFT-2048 (DIF, natural in -> bitrev out) of psf per (h,f); zero-padded.
__global__ void k3_psf_fft(const float2* __restrict__ Pc, float2* __restrict__ Pf) {
    __shared__ float2 buf[NSEQ];
    __shared__ float2 twd[1024];
    int h = blockIdx.x / NF, f = blockIdx.x % NF;
    for (int i = threadIdx.x; i < 1024; i += 256) {
        float ang = -6.28318530717958647692f * (float)i / 2048.0f;
        twd[i] = make_float2(cosf(ang), sinf(ang));
    }
    const float2* src = Pc + (size_t)(h * NF + f) * SL;
    for (int i = threadIdx.x; i < NSEQ; i += 256)
        buf[i] = (i < SL) ? src[i] : make_float2(0.f, 0.f);
    __syncthreads();
    for (int m = 1024; m >= 1; m >>= 1) {
        int stride = 1024 / m;
        for (int k = threadIdx.x; k < 1024; k += 256) {
            int j = k & (m - 1);
            int i0 = ((k - j) << 1) + j;
            int i1 = i0 + m;
            float2 a = buf[i0], b = buf[i1];
            float2 w = twd[j * stride];
            buf[i0] = cadd(a, b);
            buf[i1] = cmul(csub(a, b), w);
        }
        __syncthreads();
    }
    float2* dst = Pf + (size_t)(h * NF + f) * NSEQ;
    for (int i = threadIdx.x; i < NSEQ; i += 256) dst[i] = buf[i];
}

// K4m: channel DFT-64 as split-bf16 MFMA. Per block: (bh, 128-row t-tile).
// D[t][c] = sum_e emb[t][e] * B[c][e], c<33: cos, 33<=c<66: -sin. Write planes XcRe/XcIm.
__global__ __launch_bounds__(256) void k4_mfma(const float* __restrict__ emb,
                                               float* __restrict__ XcRe, float* __restrict__ XcIm) {
    __shared__ union {
        struct { float Emb[128][65]; float Cm[80][65]; } s;   // 33280 + 20800 B
        float Dl[66][133];                                     // 35112 B
    } u;
    const int t0 = blockIdx.x * 128;
    const int bh = blockIdx.y;
    const int b = bh / NH, h = bh % NH;
    const int tid = threadIdx.x, lane = tid & 63, w = tid >> 6;

    // stage emb tile [128][64] fp32
    for (int i = tid; i < 128 * 16; i += 256) {
        int r = i >> 4, q = i & 15;
        float4 v = *(const float4*)&emb[((size_t)b * SL + t0 + r) * ED + h * 64 + q * 4];
        u.s.Emb[r][q * 4 + 0] = v.x; u.s.Emb[r][q * 4 + 1] = v.y;
        u.s.Emb[r][q * 4 + 2] = v.z; u.s.Emb[r][q * 4 + 3] = v.w;
    }
    // stage DFT matrix B[c][e]: c<33 cos(2pi c e/64); c<66: -sin(2pi (c-33) e/64); else 0
    for (int i = tid; i < 80 * 64; i += 256) {
        int c = i >> 6, e = i & 63;
        float val = 0.f;
        if (c < 33) {
            int m = (c * e) & 63;
            val = cosf(0.09817477042468103870f * (float)m);   // 2pi/64
        } else if (c < 66) {
            int m = ((c - 33) * e) & 63;
            val = -sinf(0.09817477042468103870f * (float)m);
        }
        u.s.Cm[c][e] = val;
    }
    __syncthreads();

    // MFMA: M=128 (4 waves x 2 frags), N=80 (5 frags), K=64 (2 steps)
    f32x4 acc[2][5] = {};
    const int lr = lane & 15, lg = lane >> 4;
    #pragma unroll
    for (int ks = 0; ks < 64; ks += 32) {
        const int kg = ks + lg * 8;
        bf16x8 bh8[5], bl8[5];
        #pragma unroll
        for (int n = 0; n < 5; ++n) {
            float bv[8];
            #pragma unroll
            for (int j = 0; j < 8; ++j) bv[j] = u.s.Cm[n * 16 + lr][kg + j];
            cvt8(bv, bh8[n], bl8[n]);
        }
        #pragma unroll
        for (int m = 0; m < 2; ++m) {
            float av[8];
            const int row = w * 32 + m * 16 + lr;
            #pragma unroll
            for (int j = 0; j < 8; ++j) av[j] = u.s.Emb[row][kg + j];
            bf16x8 ah8, al8;
            cvt8(av, ah8, al8);
            #pragma unroll
            for (int n = 0; n < 5; ++n) {
                acc[m][n] = __builtin_amdgcn_mfma_f32_16x16x32_bf16(ah8, bh8[n], acc[m][n], 0, 0, 0);
                acc[m][n] = __builtin_amdgcn_mfma_f32_16x16x32_bf16(ah8, bl8[n], acc[m][n], 0, 0, 0);
                acc[m][n] = __builtin_amdgcn_mfma_f32_16x16x32_bf16(al8, bh8[n], acc[m][n], 0, 0, 0);
            }
        }
    }
    __syncthreads();
    // transpose via LDS: Dl[c][t_local]
    #pragma unroll
    for (int n = 0; n < 5; ++n) {
        int c = n * 16 + lr;
        if (c < 66) {
            #pragma unroll
            for (int m = 0; m < 2; ++m)
                #pragma unroll
                for (int j = 0; j < 4; ++j)
                    u.Dl[c][w * 32 + m * 16 + lg * 4 + j] = acc[m][n][j];
        }
    }
    __syncthreads();
    for (int i = tid; i < 66 * 128; i += 256) {
        int c = i >> 7, t = i & 127;
        float val = u.Dl[c][t];
        if (c < 33) XcRe[(size_t)(bh * NF + c) * SL + t0 + t] = val;
        else        XcIm[(size_t)(bh * NF + (c - 33)) * SL + t0 + t] = val;
    }
}

// K5: per (b,h,f): FFT-2048 (DIF) -> pointwise * Pf -> iFFT-2048 (DIT) -> write back t<1024 (in-place).
__global__ void k5_seq_conv(float* __restrict__ XcRe, float* __restrict__ XcIm,
                            const float2* __restrict__ Pf) {
    __shared__ float2 buf[NSEQ];
    __shared__ float2 twd[1024];
    int f = blockIdx.x % NF;
    int bh = blockIdx.x / NF;
    int h = bh % NH;
    for (int i = threadIdx.x; i < 1024; i += 256) {
        float ang = -6.28318530717958647692f * (float)i / 2048.0f;
        twd[i] = make_float2(cosf(ang), sinf(ang));
    }
    float* xre = XcRe + (size_t)(bh * NF + f) * SL;
    float* xim = XcIm + (size_t)(bh * NF + f) * SL;
    for (int i = threadIdx.x; i < NSEQ; i += 256)
        buf[i] = (i < SL) ? make_float2(xre[i], xim[i]) : make_float2(0.f, 0.f);
    __syncthreads();
    // forward DIF
    for (int m = 1024; m >= 1; m >>= 1) {
        int stride = 1024 / m;
        for (int k = threadIdx.x; k < 1024; k += 256) {
            int j = k & (m - 1);
            int i0 = ((k - j) << 1) + j;
            int i1 = i0 + m;
            float2 a = buf[i0], b = buf[i1];
            float2 wt = twd[j * stride];
            buf[i0] = cadd(a, b);
            buf[i1] = cmul(csub(a, b), wt);
        }
        __syncthreads();
    }
    const float2* pf = Pf + (size_t)(h * NF + f) * NSEQ;
    for (int i = threadIdx.x; i < NSEQ; i += 256)
        buf[i] = cmul(buf[i], pf[i]);
    __syncthreads();
    // inverse DIT
    for (int m = 1; m <= 1024; m <<= 1) {
        int stride = 1024 / m;
        for (int k = threadIdx.x; k < 1024; k += 256) {
            int j = k & (m - 1);
            int i0 = ((k - j) << 1) + j;
            int i1 = i0 + m;
            float2 wt = twd[j * stride];
            wt.y = -wt.y;
            float2 a = buf[i0];
            float2 bm = cmul(buf[i1], wt);
            buf[i0] = cadd(a, bm);
            buf[i1] = csub(a, bm);
        }
        __syncthreads();
    }
    const float scale = 1.0f / 2048.0f;
    for (int i = threadIdx.x; i < SL; i += 256) {
        xre[i] = buf[i].x * scale;
        xim[i] = buf[i].y * scale;
    }
}

// K6m: inverse channel DFT-64 as split-bf16 MFMA + exact GELU -> G hi/lo bf16.
// G[t][e] = sum_{c=0..63} Y[c][t] * C[c][e];  Y rows: 0..32 = Re(Y_f), 33..63 = Im(Y_f) f=1..31.
__global__ __launch_bounds__(256) void k6_mfma(const float* __restrict__ XcRe,
                                               const float* __restrict__ XcIm,
                                               ushort* __restrict__ Gh, ushort* __restrict__ Gl) {
    __shared__ float Ys[64][133];   // [c][t_local]
    __shared__ float Cm[64][65];    // [e][c]
    const int t0 = blockIdx.x * 128;
    const int bh = blockIdx.y;
    const int b = bh / NH, h = bh % NH;
    const int tid = threadIdx.x, lane = tid & 63, w = tid >> 6;

    // stage Y (transposed-read layout [c][t])
    for (int i = tid; i < 64 * 32; i += 256) {
        int c = i >> 5, tq = i & 31;
        const float* src = (c < 33) ? XcRe + (size_t)(bh * NF + c) * SL
                                    : XcIm + (size_t)(bh * NF + (c - 32)) * SL;
        float4 v = *(const float4*)&src[t0 + tq * 4];
        Ys[c][tq * 4 + 0] = v.x; Ys[c][tq * 4 + 1] = v.y;
        Ys[c][tq * 4 + 2] = v.z; Ys[c][tq * 4 + 3] = v.w;
    }
    // stage C[c][e] with Hermitian weights folded in; stored as Cm[e][c]
    for (int i = tid; i < 64 * 64; i += 256) {
        int e = i >> 6, c = i & 63;
        float v;
        if (c <= 32) {
            int m = (c * e) & 63;
            float wt = (c == 0 || c == 32) ? (1.0f / 64.0f) : (2.0f / 64.0f);
            v = wt * cosf(0.09817477042468103870f * (float)m);
        } else {
            int m = ((c - 32) * e) & 63;
            v = -(2.0f / 64.0f) * sinf(0.09817477042468103870f * (float)m);
        }
        Cm[e][c] = v;
    }
    __syncthreads();

    // MFMA: M=128 rows t (4 waves x 2), N=64 cols e (4 frags), K=64 (2 steps)
    f32x4 acc[2][4] = {};
    const int lr = lane & 15, lg = lane >> 4;
    #pragma unroll
    for (int ks = 0; ks < 64; ks += 32) {
        const int kg = ks + lg * 8;
        bf16x8 bh8[4], bl8[4];
        #pragma unroll
        for (int n = 0; n < 4; ++n) {
            float bv[8];
            #pragma unroll
            for (int j = 0; j < 8; ++j) bv[j] = Cm[n * 16 + lr][kg + j];
            cvt8(bv, bh8[n], bl8[n]);
        }
        #pragma unroll
        for (int m = 0; m < 2; ++m) {
            const int row = w * 32 + m * 16 + lr;
            float av[8];
            #pragma unroll
            for (int j = 0; j < 8; ++j) av[j] = Ys[kg + j][row];
            bf16x8 ah8, al8;
            cvt8(av, ah8, al8);
            #pragma unroll
            for (int n = 0; n < 4; ++n) {
                acc[m][n] = __builtin_amdgcn_mfma_f32_16x16x32_bf16(ah8, bh8[n], acc[m][n], 0, 0, 0);
                acc[m][n] = __builtin_amdgcn_mfma_f32_16x16x32_bf16(ah8, bl8[n], acc[m][n], 0, 0, 0);
                acc[m][n] = __builtin_amdgcn_mfma_f32_16x16x32_bf16(al8, bh8[n], acc[m][n], 0, 0, 0);
            }
        }
    }
    // epilogue: GELU + split store. D: col = lane&15, row = lg*4 + j
    #pragma unroll
    for (int n = 0; n < 4; ++n) {
        const int col = h * 64 + n * 16 + lr;
        #pragma unroll
        for (int m = 0; m < 2; ++m) {
            #pragma unroll
            for (int j = 0; j < 4; ++j) {
                int t = t0 + w * 32 + m * 16 + lg * 4 + j;
                float v = acc[m][n][j];
                float g = 0.5f * v * (1.0f + erff(v * 0.70710678118654752440f));
                size_t idx = ((size_t)b * SL + t) * ED + col;
                unsigned short hb = bf16bits(g);
                Gh[idx] = hb;
                Gl[idx] = bf16bits(g - bf16val(hb));
            }
        }
    }
}

// K0b: cast W (fp32 [768][768]) to bf16 hi/lo pair.
__global__ void k0_castW(const float* __restrict__ W,
                         ushort* __restrict__ Wh, ushort* __restrict__ Wl) {
    int i = blockIdx.x * 256 + threadIdx.x;
    if (i < ED * ED) {
        float w = W[i];
        unsigned short hb = bf16bits(w);
        Wh[i] = hb;
        Wl[i] = bf16bits(w - bf16val(hb));
    }
}

// K7: out[i][j] = sum_d G[i][d]*W[j][d] + bias[j] via bf16 split-precision MFMA.
__global__ __launch_bounds__(256) void k7_mfma(
        const ushort* __restrict__ Gh, const ushort* __restrict__ Gl,
        const ushort* __restrict__ Wh, const ushort* __restrict__ Wl,
        const float* __restrict__ bias, float* __restrict__ out) {
    __shared__ ushort Ah[128 * 32], Al[128 * 32], Bh[128 * 32], Bl[128 * 32];
    const int j0 = blockIdx.x * 128;
    const int i0 = blockIdx.y * 128;
    const int tid = threadIdx.x;
    const int lane = tid & 63, wid = tid >> 6;
    const int wm = wid >> 1, wn = wid & 1;

    const int stRow = wid * 32 + (lane >> 2);
    const int stCol = (lane & 3) * 8;
    const int ldsBase0 = wid * 1024;
    const int ldsBase1 = wid * 1024 + 512;

    f32x4 acc[4][4] = {};

    const int arow = wm * 64 + (lane & 15);
    const int brow = wn * 64 + (lane & 15);
    const int kb8  = (lane >> 4) * 8;

    for (int k0 = 0; k0 < ED; k0 += 32) {
        const ushort* gA = Gh + (size_t)(i0 + stRow) * ED + k0 + stCol;
        const ushort* gAl = Gl + (size_t)(i0 + stRow) * ED + k0 + stCol;
        const ushort* gB = Wh + (size_t)(j0 + stRow) * ED + k0 + stCol;
        const ushort* gBl = Wl + (size_t)(j0 + stRow) * ED + k0 + stCol;
        __builtin_amdgcn_global_load_lds(GLB_U32(gA), LDS_U32(&Ah[ldsBase0]), 16, 0, 0);
        __builtin_amdgcn_global_load_lds(GLB_U32(gA + 16 * ED), LDS_U32(&Ah[ldsBase1]), 16, 0, 0);
        __builtin_amdgcn_global_load_lds(GLB_U32(gAl), LDS_U32(&Al[ldsBase0]), 16, 0, 0);
        __builtin_amdgcn_global_load_lds(GLB_U32(gAl + 16 * ED), LDS_U32(&Al[ldsBase1]), 16, 0, 0);
        __builtin_amdgcn_global_load_lds(GLB_U32(gB), LDS_U32(&Bh[ldsBase0]), 16, 0, 0);
        __builtin_amdgcn_global_load_lds(GLB_U32(gB + 16 * ED), LDS_U32(&Bh[ldsBase1]), 16, 0, 0);
        __builtin_amdgcn_global_load_lds(GLB_U32(gBl), LDS_U32(&Bl[ldsBase0]), 16, 0, 0);
        __builtin_amdgcn_global_load_lds(GLB_U32(gBl + 16 * ED), LDS_U32(&Bl[ldsBase1]), 16, 0, 0);
        __syncthreads();

        bf16x8 ah[4], al[4], bh[4], bl[4];
        #pragma unroll
        for (int m = 0; m < 4; ++m) {
            ah[m] = *(const bf16x8*)&Ah[(arow + m * 16) * 32 + kb8];
            al[m] = *(const bf16x8*)&Al[(arow + m * 16) * 32 + kb8];
        }
        #pragma unroll
        for (int n = 0; n < 4; ++n) {
            bh[n] = *(const bf16x8*)&Bh[(brow + n * 16) * 32 + kb8];
            bl[n] = *(const bf16x8*)&Bl[(brow + n * 16) * 32 + kb8];
        }
        #pragma unroll
        for (int m = 0; m < 4; ++m)
            #pragma unroll
            for (int n = 0; n < 4; ++n) {
                acc[m][n] = __builtin_amdgcn_mfma_f32_16x16x32_bf16(ah[m], bh[n], acc[m][n], 0, 0, 0);
                acc[m][n] = __builtin_amdgcn_mfma_f32_16x16x32_bf16(ah[m], bl[n], acc[m][n], 0, 0, 0);
                acc[m][n] = __builtin_amdgcn_mfma_f32_16x16x32_bf16(al[m], bh[n], acc[m][n], 0, 0, 0);
            }
        __syncthreads();
    }

    const int ocol0 = j0 + wn * 64 + (lane & 15);
    const int orow0 = i0 + wm * 64 + (lane >> 4) * 4;
    #pragma unroll
    for (int n = 0; n < 4; ++n) {
        const float bv = bias[ocol0 + n * 16];
        #pragma unroll
        for (int m = 0; m < 4; ++m) {
            #pragma unroll
            for (int j = 0; j < 4; ++j) {
                out[(size_t)(orow0 + m * 16 + j) * ED + ocol0 + n * 16] = acc[m][n][j] + bv;
            }
        }
    }
}

extern "C" void kernel_launch(void* const* d_in, const int* in_sizes, int n_in,
                              void* d_out, int out_size, void* d_ws, size_t ws_size,
                              hipStream_t stream) {
    (void)in_sizes; (void)n_in; (void)out_size; (void)ws_size;
    const float* emb  = (const float*)d_in[0];   // [8,1024,768]
    const float* tp   = (const float*)d_in[1];   // [12,2047,64]
    const float* W    = (const float*)d_in[2];   // [768,768]
    const float* bias = (const float*)d_in[3];   // [768]

    float* out_conv = (float*)d_out;                             // 8*1024*768
    float* out_psf  = out_conv + (size_t)NB * SL * ED;           // 12*2047*64

    // workspace layout:
    float2* Pc = (float2*)d_ws;                                  // 12*33*1024 complex (dead after k3)
    float2* Pf = Pc + (size_t)NH * NF * SL;                      // 12*33*2048 complex
    float*  XcRe = (float*)(Pf + (size_t)NH * NF * NSEQ);        // 96*33*1024 f32
    float*  XcIm = XcRe + (size_t)NB * NH * NF * SL;             // 96*33*1024 f32
    ushort* Gh = (ushort*)(XcIm + (size_t)NB * NH * NF * SL);    // 8192*768 bf16
    ushort* Gl = Gh + (size_t)NB * SL * ED;                      // 8192*768 bf16
    // W hi/lo overlaid on Pc (2.36 MB <= 3.24 MB), launched after k3 consumes Pc
    ushort* Whh = (ushort*)Pc;
    ushort* Wll = Whh + (size_t)ED * ED;

    k1_softmax<<<dim3(NH * 64), dim3(256), 0, stream>>>(tp, out_psf);
    k2_psf_cdft<<<dim3(SL / 64, NH), dim3(256), 0, stream>>>(out_psf, Pc);
    k3_psf_fft<<<dim3(NH * NF), dim3(256), 0, stream>>>(Pc, Pf);
    k0_castW<<<dim3((ED * ED + 255) / 256), dim3(256), 0, stream>>>(W, Whh, Wll);
    k4_mfma<<<dim3(SL / 128, NB * NH), dim3(256), 0, stream>>>(emb, XcRe, XcIm);
    k5_seq_conv<<<dim3(NB * NH * NF), dim3(256), 0, stream>>>(XcRe, XcIm, Pf);
    k6_mfma<<<dim3(SL / 128, NB * NH), dim3(256), 0, stream>>>(XcRe, XcIm, Gh, Gl);
    k7_mfma<<<dim3(ED / 128, (NB * SL) / 128), dim3(256), 0, stream>>>(
        Gh, Gl, Whh, Wll, bias, out_conv);
}